// Round 9
// baseline (269.588 us; speedup 1.0000x reference)
//
#include <hip/hip_runtime.h>
#include <math.h>

#define NNODES 50000
#define NEDGES 800000
#define COUT 64
#define TILE_E 64
#define NTILES (NEDGES / TILE_E)   // 12500, exact
#define GRID 1792                  // 256 CU x 7 blocks (LDS 20736B -> 7/CU)
#define KEY_NEG_INF 0x007FFFFFu    // fkey(-inf)
#define NB1 391                    // coarse buckets (dst>>7) and P1 chunks
#define NB1P 392                   // padded stride
#define CHUNK 2048                 // edges per P1 block
#define P2CAP 2816                 // LDS rec capacity per bucket

typedef short bf16x8 __attribute__((ext_vector_type(8)));
typedef float f32x4 __attribute__((ext_vector_type(4)));
#define MFMA16 __builtin_amdgcn_mfma_f32_16x16x32_bf16

// fp32 -> bf16 RTNE
__device__ __forceinline__ unsigned short f2bf(float x) {
    union { float f; unsigned u; } v; v.f = x;
    unsigned r = v.u + 0x7fffu + ((v.u >> 16) & 1u);
    return (unsigned short)(r >> 16);
}

// order-preserving float -> uint key
__device__ __forceinline__ unsigned fkey(float v) {
    unsigned u = __float_as_uint(v);
    return u ^ ((unsigned)((int)u >> 31) | 0x80000000u);
}

// ---------------------------------------------------------------------------
// prep: feat f32 -> bf16 table; out <- key(-inf)
// ---------------------------------------------------------------------------
__global__ void prep_kernel(const float* __restrict__ feat, unsigned short* __restrict__ featbf,
                            unsigned* __restrict__ out) {
    int i = blockIdx.x * blockDim.x + threadIdx.x;
    int st = gridDim.x * blockDim.x;
    for (int j = i; j < (NNODES * COUT) / 8; j += st) {
        const float4* pp = (const float4*)(feat + (size_t)j * 8);
        float4 x = pp[0], y = pp[1];
        union { unsigned short u[8]; uint4 v; } r;
        r.u[0] = f2bf(x.x); r.u[1] = f2bf(x.y); r.u[2] = f2bf(x.z); r.u[3] = f2bf(x.w);
        r.u[4] = f2bf(y.x); r.u[5] = f2bf(y.y); r.u[6] = f2bf(y.z); r.u[7] = f2bf(y.w);
        ((uint4*)featbf)[j] = r.v;
    }
    for (int j = i; j < NNODES * COUT; j += st) out[j] = KEY_NEG_INF;
}

// ---------------------------------------------------------------------------
// P1a: per-chunk LDS histogram of coarse bucket (dst>>7), coalesced store
// ---------------------------------------------------------------------------
__global__ __launch_bounds__(256) void p1a_kernel(const int* __restrict__ ei,
                                                  unsigned* __restrict__ cnt1) {
    __shared__ unsigned h[NB1];
    const int t = threadIdx.x, blk = blockIdx.x;
    for (int i = t; i < NB1; i += 256) h[i] = 0u;
    __syncthreads();
    const int e0 = blk * CHUNK;
    for (int i = t; i < CHUNK; i += 256) {
        int e = e0 + i;
        if (e < NEDGES) atomicAdd(&h[(unsigned)ei[NEDGES + e] >> 7], 1u);
    }
    __syncthreads();
    for (int i = t; i < NB1; i += 256) cnt1[blk * NB1P + i] = h[i];
}

// ---------------------------------------------------------------------------
// P1b: per bucket b, exclusive scan over blocks of cnt1[blk][b]; totals[b]
// ---------------------------------------------------------------------------
__global__ __launch_bounds__(512) void p1b_kernel(const unsigned* __restrict__ cnt1,
                                                  unsigned* __restrict__ off0,
                                                  unsigned* __restrict__ totals) {
    __shared__ unsigned sh[512];
    const int t = threadIdx.x, b = blockIdx.x;
    unsigned v = (t < NB1) ? cnt1[t * NB1P + b] : 0u;
    sh[t] = v;
    __syncthreads();
    for (int off = 1; off < 512; off <<= 1) {
        unsigned add = (t >= off) ? sh[t - off] : 0u;
        __syncthreads();
        sh[t] += add;
        __syncthreads();
    }
    if (t < NB1) off0[t * NB1P + b] = sh[t] - v;
    if (t == 511) totals[b] = sh[511];
}

// P1c: exclusive scan of totals[391] -> base[392]
__global__ __launch_bounds__(512) void p1c_kernel(const unsigned* __restrict__ totals,
                                                  unsigned* __restrict__ base) {
    __shared__ unsigned sh[512];
    const int t = threadIdx.x;
    unsigned v = (t < NB1) ? totals[t] : 0u;
    sh[t] = v;
    __syncthreads();
    for (int off = 1; off < 512; off <<= 1) {
        unsigned add = (t >= off) ? sh[t - off] : 0u;
        __syncthreads();
        sh[t] += add;
        __syncthreads();
    }
    if (t <= NB1) base[t] = sh[t] - v;   // t==391: v=0 -> total sum
}

// ---------------------------------------------------------------------------
// P1d: scatter edges into coarse-bucket-grouped rec (LDS ranks)
// ---------------------------------------------------------------------------
__global__ __launch_bounds__(256) void p1d_kernel(const int* __restrict__ ei,
                                                  const int* __restrict__ ea,
                                                  const unsigned* __restrict__ off0,
                                                  const unsigned* __restrict__ base,
                                                  int2* __restrict__ rec) {
    __shared__ unsigned h[NB1];
    const int t = threadIdx.x, blk = blockIdx.x;
    for (int i = t; i < NB1; i += 256) h[i] = 0u;
    __syncthreads();
    const int e0 = blk * CHUNK;
    for (int i = t; i < CHUNK; i += 256) {
        int e = e0 + i;
        if (e < NEDGES) {
            int d = ei[NEDGES + e];
            unsigned b = (unsigned)d >> 7;
            unsigned rk = atomicAdd(&h[b], 1u);
            unsigned pos = base[b] + off0[blk * NB1P + b] + rk;
            rec[pos] = make_int2(ei[e] | (ea[e] << 20), d);
        }
    }
}

// ---------------------------------------------------------------------------
// P2: per-bucket full sort by dst (128 bins), in place via LDS buffer
// ---------------------------------------------------------------------------
__global__ __launch_bounds__(512) void p2_kernel(const unsigned* __restrict__ base,
                                                 int2* __restrict__ rec) {
    __shared__ int2 buf[P2CAP];
    __shared__ unsigned hist[128], dbase[128];
    const int t = threadIdx.x, b = blockIdx.x;
    const unsigned lo = base[b];
    int n = (int)(base[b + 1] - lo);
    if (n > P2CAP) n = P2CAP;        // statistically unreachable
    for (int i = t; i < 128; i += 512) hist[i] = 0u;
    __syncthreads();
    for (int i = t; i < n; i += 512) {
        int2 r = rec[lo + i];
        buf[i] = r;
        atomicAdd(&hist[r.y & 127], 1u);
    }
    __syncthreads();
    if (t < 64) {                    // wave 0: scan 128 bins, 2 per lane
        unsigned h0 = hist[2 * t], h1 = hist[2 * t + 1];
        unsigned s = h0 + h1;
        unsigned inc = s;
        #pragma unroll
        for (int off = 1; off < 64; off <<= 1) {
            unsigned nb = __shfl_up(inc, off, 64);
            if (t >= off) inc += nb;
        }
        unsigned excl = inc - s;
        dbase[2 * t] = excl;
        dbase[2 * t + 1] = excl + h0;
    }
    __syncthreads();
    for (int i = t; i < 128; i += 512) hist[i] = 0u;   // reuse as rank counters
    __syncthreads();
    for (int i = t; i < n; i += 512) {
        int2 r = buf[i];
        int ld = r.y & 127;
        unsigned rk = atomicAdd(&hist[ld], 1u);
        rec[lo + dbase[ld] + rk] = r;
    }
}

__global__ void finalize_kernel(float* __restrict__ out, int n) {
    int i = blockIdx.x * blockDim.x + threadIdx.x;
    int stride = gridDim.x * blockDim.x;
    for (; i < n; i += stride) {
        unsigned k = ((unsigned*)out)[i];
        unsigned u = (k & 0x80000000u) ? (k ^ 0x80000000u) : ~k;
        out[i] = (u == 0xFF800000u) ? 0.0f : __uint_as_float(u);
    }
}

// per-lane segmented max over 4 consecutive sorted rows, two columns at once
__device__ __forceinline__ void flush4x2(const f32x4& a, const f32x4& bq, int R,
                                         const int* __restrict__ dv,
                                         int col0, int col1,
                                         unsigned* __restrict__ out) {
    int curd = dv[R];
    unsigned ca = fkey(a[0]), cb = fkey(bq[0]);
    #pragma unroll
    for (int j = 1; j < 4; ++j) {
        int d = dv[R + j];
        unsigned ka = fkey(a[j]), kb = fkey(bq[j]);
        if (d == curd) {
            ca = (ka > ca) ? ka : ca;
            cb = (kb > cb) ? kb : cb;
        } else {
            atomicMax(out + (size_t)curd * COUT + col0, ca);
            atomicMax(out + (size_t)curd * COUT + col1, cb);
            curd = d; ca = ka; cb = kb;
        }
    }
    atomicMax(out + (size_t)curd * COUT + col0, ca);
    atomicMax(out + (size_t)curd * COUT + col1, cb);
}

// ---------------------------------------------------------------------------
// MFMA edge kernel v2: no key-transpose buffer. In-register segmented flush
// straight from MFMA accumulators (4 sorted rows live in each lane).
// LDS = Amsg 20480B + dstv 256B = 20736B -> 7 blocks/CU.
// Per tile: stage -> B1 -> MFMA -> in-lane flush (atomics) -> B2.
// ---------------------------------------------------------------------------
__global__ __launch_bounds__(256, 7) void edge_mfma_kernel(
    const unsigned short* __restrict__ featbf, const float* __restrict__ pos,
    const float* __restrict__ W, const float* __restrict__ b,
    const int2* __restrict__ rec, unsigned* __restrict__ out)
{
    __shared__ char SMEM[20736];
    bf16x8* Amsg = (bf16x8*)SMEM;               // [20][64] 16B units, 20480 B
    int*    dstv = (int*)(SMEM + 20480);        // [64]

    const int tid = threadIdx.x;
    const int lane = tid & 63, w = tid >> 6;
    const int rg = w >> 1, cg = w & 1;
    const int la = lane & 15, lh = lane >> 4;
    const bf16x8 zero8 = {0, 0, 0, 0, 0, 0, 0, 0};

    // ---- stage W_aug [col j][k 0..159] bf16 into SMEM (one-time) ----
    {
        unsigned short* Ws = (unsigned short*)SMEM;   // 64*160*2 = 20480 B
        for (int idx = tid; idx < 160 * 64; idx += 256) {
            int k = idx >> 6, j = idx & 63;           // coalesced over j
            int t = (k >= 80);
            int kk = k - t * 80;
            float v = 0.0f;
            if (kk < 71)       v = W[(t * 71 + kk) * 64 + j];
            else if (kk == 71) v = b[t * 64 + j];
            Ws[j * 160 + k] = f2bf(v);
        }
    }
    __syncthreads();
    bf16x8 wb0[5], wb1[5];
    {
        const bf16x8* Wv = (const bf16x8*)SMEM;       // frag = Wv[col*20 + slot]
        const int c0 = cg * 32 + la, c1 = c0 + 16;
        #pragma unroll
        for (int ks = 0; ks < 5; ++ks) {
            wb0[ks] = Wv[c0 * 20 + ks * 4 + lh];
            wb1[ks] = Wv[c1 * 20 + ks * 4 + lh];
        }
    }
    __syncthreads();                                  // all frags held
    // one-time zero of slots 9 and 19 (never written in the loop)
    if (tid < 128) {
        Amsg[(9 + (tid >> 6) * 10) * 64 + (tid & 63)] = zero8;
    }
    __syncthreads();

    const int row = tid >> 2, c = tid & 3;

    for (int tile = blockIdx.x; tile < NTILES; tile += GRID) {
        // ---------------- stage 64 sorted edges ----------------
        const int2 r2 = rec[tile * TILE_E + row];
        const int src = r2.x & 0xFFFFF;
        const int t = r2.x >> 20;
        const int ot = 1 - t;

        const uint4* g = (const uint4*)(featbf + (size_t)src * 64);   // 8x16B
        uint4 q0 = g[2 * c], q1 = g[2 * c + 1];
        *(uint4*)&Amsg[(t * 10 + 2 * c) * 64 + row]     = q0;
        *(uint4*)&Amsg[(t * 10 + 2 * c + 1) * 64 + row] = q1;
        Amsg[(ot * 10 + 2 * c) * 64 + row]     = zero8;
        Amsg[(ot * 10 + 2 * c + 1) * 64 + row] = zero8;

        if (c == 0) {
            int dst = r2.y;
            float ps0 = pos[src * 3], ps1 = pos[src * 3 + 1], ps2 = pos[src * 3 + 2];
            float d0 = pos[dst * 3] - ps0, d1 = pos[dst * 3 + 1] - ps1, d2 = pos[dst * 3 + 2] - ps2;
            float dist = sqrtf(d0 * d0 + d1 * d1 + d2 * d2);
            union { bf16x8 v; unsigned short u[8]; } pt;
            pt.u[0] = f2bf(ps0); pt.u[1] = f2bf(ps1); pt.u[2] = f2bf(ps2);
            pt.u[3] = f2bf(d0);  pt.u[4] = f2bf(d1);  pt.u[5] = f2bf(d2);
            pt.u[6] = f2bf(dist); pt.u[7] = f2bf(1.0f);
            Amsg[(t * 10 + 8) * 64 + row] = pt.v;
        } else if (c == 1) {
            Amsg[(ot * 10 + 8) * 64 + row] = zero8;
        } else if (c == 3) {
            dstv[row] = r2.y;
        }
        __syncthreads();                                   // B1: tile staged

        // ---------------- mfma: 32x32 tile per wave, W from regs ----------------
        f32x4 acc00 = {0,0,0,0}, acc01 = {0,0,0,0}, acc10 = {0,0,0,0}, acc11 = {0,0,0,0};
        const int r0 = rg * 32 + la, r1 = r0 + 16;
        #pragma unroll
        for (int ks = 0; ks < 5; ++ks) {
            bf16x8 a0 = Amsg[(ks * 4 + lh) * 64 + r0];
            bf16x8 a1 = Amsg[(ks * 4 + lh) * 64 + r1];
            acc00 = MFMA16(a0, wb0[ks], acc00, 0, 0, 0);
            acc01 = MFMA16(a0, wb1[ks], acc01, 0, 0, 0);
            acc10 = MFMA16(a1, wb0[ks], acc10, 0, 0, 0);
            acc11 = MFMA16(a1, wb1[ks], acc11, 0, 0, 0);
        }

        // ---- in-register segmented flush (rows sorted by dst) ----
        {
            const int col0 = cg * 32 + la, col1 = col0 + 16;
            const int R0 = rg * 32 + lh * 4;    // rows of acc00/acc01
            flush4x2(acc00, acc01, R0,      dstv, col0, col1, out);
            flush4x2(acc10, acc11, R0 + 16, dstv, col0, col1, out);
        }
        __syncthreads();                                   // B2: Amsg/dstv free
    }
}

extern "C" void kernel_launch(void* const* d_in, const int* in_sizes, int n_in,
                              void* d_out, int out_size, void* d_ws, size_t ws_size,
                              hipStream_t stream) {
    const float* feat = (const float*)d_in[0];
    const float* pos  = (const float*)d_in[1];
    const float* W    = (const float*)d_in[2];
    const float* b    = (const float*)d_in[3];
    const int*   ei   = (const int*)d_in[4];
    const int*   ea   = (const int*)d_in[5];
    unsigned* out = (unsigned*)d_out;

    // ws: featbf 6.4MB | rec 6.4MB | cnt1 612KB | off0 612KB | totals | base
    unsigned short* featbf = (unsigned short*)d_ws;
    int2*     rec    = (int2*)((char*)d_ws + (size_t)NNODES * COUT * 2);
    unsigned* cnt1   = (unsigned*)(rec + NEDGES);
    unsigned* off0   = cnt1 + NB1 * NB1P;
    unsigned* totals = off0 + NB1 * NB1P;
    unsigned* base   = totals + NB1P;

    prep_kernel<<<2048, 256, 0, stream>>>(feat, featbf, out);
    p1a_kernel<<<NB1, 256, 0, stream>>>(ei, cnt1);
    p1b_kernel<<<NB1, 512, 0, stream>>>(cnt1, off0, totals);
    p1c_kernel<<<1, 512, 0, stream>>>(totals, base);
    p1d_kernel<<<NB1, 256, 0, stream>>>(ei, ea, off0, base, rec);
    p2_kernel<<<NB1, 512, 0, stream>>>(base, rec);
    edge_mfma_kernel<<<GRID, 256, 0, stream>>>(featbf, pos, W, b, rec, out);
    finalize_kernel<<<2048, 256, 0, stream>>>((float*)out, NNODES * COUT);
}

// Round 10
// 179.660 us; speedup vs baseline: 1.5005x; 1.5005x over previous
//
#include <hip/hip_runtime.h>
#include <math.h>

#define NNODES 50000
#define NEDGES 800000
#define COUT 64
#define TILE_E 64
#define NTILES (NEDGES / TILE_E)   // 12500, exact
#define GRID 1024                  // 256 CU x 4 blocks
#define KEY_NEG_INF 0x007FFFFFu    // fkey(-inf)
#define NB1 391                    // coarse buckets (dst>>7) and P1 chunks
#define NB1P 392                   // padded stride
#define CHUNK 2048                 // edges per P1 block
#define P2CAP 2816                 // LDS rec capacity per bucket

typedef short bf16x8 __attribute__((ext_vector_type(8)));
typedef float f32x4 __attribute__((ext_vector_type(4)));
#define MFMA16 __builtin_amdgcn_mfma_f32_16x16x32_bf16

// fp32 -> bf16 RTNE
__device__ __forceinline__ unsigned short f2bf(float x) {
    union { float f; unsigned u; } v; v.f = x;
    unsigned r = v.u + 0x7fffu + ((v.u >> 16) & 1u);
    return (unsigned short)(r >> 16);
}

// order-preserving float -> uint key
__device__ __forceinline__ unsigned fkey(float v) {
    unsigned u = __float_as_uint(v);
    return u ^ ((unsigned)((int)u >> 31) | 0x80000000u);
}

// LDS-only barrier: waits DS ops (lgkmcnt) but NOT vmem/atomics (vmcnt).
// m201-template pattern; sched_barrier pins ordering around it.
__device__ __forceinline__ void soft_barrier() {
    __builtin_amdgcn_sched_barrier(0);
    asm volatile("s_waitcnt lgkmcnt(0)" ::: "memory");
    __builtin_amdgcn_s_barrier();
    __builtin_amdgcn_sched_barrier(0);
}

// ---------------------------------------------------------------------------
// prep: feat f32 -> bf16 table; out <- key(-inf)
// ---------------------------------------------------------------------------
__global__ void prep_kernel(const float* __restrict__ feat, unsigned short* __restrict__ featbf,
                            unsigned* __restrict__ out) {
    int i = blockIdx.x * blockDim.x + threadIdx.x;
    int st = gridDim.x * blockDim.x;
    for (int j = i; j < (NNODES * COUT) / 8; j += st) {
        const float4* pp = (const float4*)(feat + (size_t)j * 8);
        float4 x = pp[0], y = pp[1];
        union { unsigned short u[8]; uint4 v; } r;
        r.u[0] = f2bf(x.x); r.u[1] = f2bf(x.y); r.u[2] = f2bf(x.z); r.u[3] = f2bf(x.w);
        r.u[4] = f2bf(y.x); r.u[5] = f2bf(y.y); r.u[6] = f2bf(y.z); r.u[7] = f2bf(y.w);
        ((uint4*)featbf)[j] = r.v;
    }
    for (int j = i; j < NNODES * COUT; j += st) out[j] = KEY_NEG_INF;
}

// ---------------------------------------------------------------------------
// P1a: per-chunk LDS histogram of coarse bucket (dst>>7), coalesced store
// ---------------------------------------------------------------------------
__global__ __launch_bounds__(256) void p1a_kernel(const int* __restrict__ ei,
                                                  unsigned* __restrict__ cnt1) {
    __shared__ unsigned h[NB1];
    const int t = threadIdx.x, blk = blockIdx.x;
    for (int i = t; i < NB1; i += 256) h[i] = 0u;
    __syncthreads();
    const int e0 = blk * CHUNK;
    for (int i = t; i < CHUNK; i += 256) {
        int e = e0 + i;
        if (e < NEDGES) atomicAdd(&h[(unsigned)ei[NEDGES + e] >> 7], 1u);
    }
    __syncthreads();
    for (int i = t; i < NB1; i += 256) cnt1[blk * NB1P + i] = h[i];
}

// ---------------------------------------------------------------------------
// P1b: per bucket b, exclusive scan over blocks of cnt1[blk][b]; totals[b]
// ---------------------------------------------------------------------------
__global__ __launch_bounds__(512) void p1b_kernel(const unsigned* __restrict__ cnt1,
                                                  unsigned* __restrict__ off0,
                                                  unsigned* __restrict__ totals) {
    __shared__ unsigned sh[512];
    const int t = threadIdx.x, b = blockIdx.x;
    unsigned v = (t < NB1) ? cnt1[t * NB1P + b] : 0u;
    sh[t] = v;
    __syncthreads();
    for (int off = 1; off < 512; off <<= 1) {
        unsigned add = (t >= off) ? sh[t - off] : 0u;
        __syncthreads();
        sh[t] += add;
        __syncthreads();
    }
    if (t < NB1) off0[t * NB1P + b] = sh[t] - v;
    if (t == 511) totals[b] = sh[511];
}

// P1c: exclusive scan of totals[391] -> base[392]
__global__ __launch_bounds__(512) void p1c_kernel(const unsigned* __restrict__ totals,
                                                  unsigned* __restrict__ base) {
    __shared__ unsigned sh[512];
    const int t = threadIdx.x;
    unsigned v = (t < NB1) ? totals[t] : 0u;
    sh[t] = v;
    __syncthreads();
    for (int off = 1; off < 512; off <<= 1) {
        unsigned add = (t >= off) ? sh[t - off] : 0u;
        __syncthreads();
        sh[t] += add;
        __syncthreads();
    }
    if (t <= NB1) base[t] = sh[t] - v;   // t==391: v=0 -> total sum
}

// ---------------------------------------------------------------------------
// P1d: scatter edges into coarse-bucket-grouped rec (LDS ranks)
// ---------------------------------------------------------------------------
__global__ __launch_bounds__(256) void p1d_kernel(const int* __restrict__ ei,
                                                  const int* __restrict__ ea,
                                                  const unsigned* __restrict__ off0,
                                                  const unsigned* __restrict__ base,
                                                  int2* __restrict__ rec) {
    __shared__ unsigned h[NB1];
    const int t = threadIdx.x, blk = blockIdx.x;
    for (int i = t; i < NB1; i += 256) h[i] = 0u;
    __syncthreads();
    const int e0 = blk * CHUNK;
    for (int i = t; i < CHUNK; i += 256) {
        int e = e0 + i;
        if (e < NEDGES) {
            int d = ei[NEDGES + e];
            unsigned b = (unsigned)d >> 7;
            unsigned rk = atomicAdd(&h[b], 1u);
            unsigned pos = base[b] + off0[blk * NB1P + b] + rk;
            rec[pos] = make_int2(ei[e] | (ea[e] << 20), d);
        }
    }
}

// ---------------------------------------------------------------------------
// P2: per-bucket full sort by dst (128 bins), in place via LDS buffer
// ---------------------------------------------------------------------------
__global__ __launch_bounds__(512) void p2_kernel(const unsigned* __restrict__ base,
                                                 int2* __restrict__ rec) {
    __shared__ int2 buf[P2CAP];
    __shared__ unsigned hist[128], dbase[128];
    const int t = threadIdx.x, b = blockIdx.x;
    const unsigned lo = base[b];
    int n = (int)(base[b + 1] - lo);
    if (n > P2CAP) n = P2CAP;        // statistically unreachable
    for (int i = t; i < 128; i += 512) hist[i] = 0u;
    __syncthreads();
    for (int i = t; i < n; i += 512) {
        int2 r = rec[lo + i];
        buf[i] = r;
        atomicAdd(&hist[r.y & 127], 1u);
    }
    __syncthreads();
    if (t < 64) {                    // wave 0: scan 128 bins, 2 per lane
        unsigned h0 = hist[2 * t], h1 = hist[2 * t + 1];
        unsigned s = h0 + h1;
        unsigned inc = s;
        #pragma unroll
        for (int off = 1; off < 64; off <<= 1) {
            unsigned nb = __shfl_up(inc, off, 64);
            if (t >= off) inc += nb;
        }
        unsigned excl = inc - s;
        dbase[2 * t] = excl;
        dbase[2 * t + 1] = excl + h0;
    }
    __syncthreads();
    for (int i = t; i < 128; i += 512) hist[i] = 0u;   // reuse as rank counters
    __syncthreads();
    for (int i = t; i < n; i += 512) {
        int2 r = buf[i];
        int ld = r.y & 127;
        unsigned rk = atomicAdd(&hist[ld], 1u);
        rec[lo + dbase[ld] + rk] = r;
    }
}

__global__ void finalize_kernel(float* __restrict__ out, int n) {
    int i = blockIdx.x * blockDim.x + threadIdx.x;
    int stride = gridDim.x * blockDim.x;
    for (; i < n; i += stride) {
        unsigned k = ((unsigned*)out)[i];
        unsigned u = (k & 0x80000000u) ? (k ^ 0x80000000u) : ~k;
        out[i] = (u == 0xFF800000u) ? 0.0f : __uint_as_float(u);
    }
}

// ---------------------------------------------------------------------------
// MFMA edge kernel v3 = round-8 structure + lgkm-only barriers (atomics and
// prefetch loads never drained at barriers) + T14 register prefetch of the
// next tile's rec/feat/pos gathers (issued under MFMA / segscan phases).
// LDS 37376B -> 4 blocks/CU. 2 soft barriers/tile.
// ---------------------------------------------------------------------------
__global__ __launch_bounds__(256, 4) void edge_mfma_kernel(
    const unsigned short* __restrict__ featbf, const float* __restrict__ pos,
    const float* __restrict__ W, const float* __restrict__ b,
    const int2* __restrict__ rec, unsigned* __restrict__ out)
{
    __shared__ char SMEM[37376];
    bf16x8*   Amsg = (bf16x8*)SMEM;               // [20][64] 16B units, 20480 B
    unsigned* Kt   = (unsigned*)(SMEM + 20480);   // [4096], 16384 B
    int*      dstv = (int*)(SMEM + 36864);        // [2][64]

    const int tid = threadIdx.x;
    const int lane = tid & 63, w = tid >> 6;
    const int rg = w >> 1, cg = w & 1;
    const int la = lane & 15, lh = lane >> 4;
    const bf16x8 zero8 = {0, 0, 0, 0, 0, 0, 0, 0};
    const int row = tid >> 2, c = tid & 3;

    // ---- issue tile-0 gathers immediately (overlap W staging below) ----
    int tile = blockIdx.x;
    int2 r2 = rec[tile * TILE_E + row];
    {
        // nothing else; loads below chain off r2
    }
    int src0 = r2.x & 0xFFFFF;
    const uint4* g0 = (const uint4*)(featbf + (size_t)src0 * 64);
    uint4 q0 = g0[2 * c], q1 = g0[2 * c + 1];
    float cps0 = 0.f, cps1 = 0.f, cps2 = 0.f, cpd0 = 0.f, cpd1 = 0.f, cpd2 = 0.f;
    if (c == 0) {
        cps0 = pos[src0 * 3]; cps1 = pos[src0 * 3 + 1]; cps2 = pos[src0 * 3 + 2];
        int d0i = r2.y;
        cpd0 = pos[d0i * 3]; cpd1 = pos[d0i * 3 + 1]; cpd2 = pos[d0i * 3 + 2];
    }

    // ---- stage W_aug [col j][k 0..159] bf16 into SMEM (one-time) ----
    {
        unsigned short* Ws = (unsigned short*)SMEM;   // 64*160*2 = 20480 B
        for (int idx = tid; idx < 160 * 64; idx += 256) {
            int k = idx >> 6, j = idx & 63;           // coalesced over j
            int t = (k >= 80);
            int kk = k - t * 80;
            float v = 0.0f;
            if (kk < 71)       v = W[(t * 71 + kk) * 64 + j];
            else if (kk == 71) v = b[t * 64 + j];
            Ws[j * 160 + k] = f2bf(v);
        }
    }
    __syncthreads();
    bf16x8 wb0[5], wb1[5];
    {
        const bf16x8* Wv = (const bf16x8*)SMEM;       // frag = Wv[col*20 + slot]
        const int c0 = cg * 32 + la, c1 = c0 + 16;
        #pragma unroll
        for (int ks = 0; ks < 5; ++ks) {
            wb0[ks] = Wv[c0 * 20 + ks * 4 + lh];
            wb1[ks] = Wv[c1 * 20 + ks * 4 + lh];
        }
    }
    __syncthreads();                                  // all frags held
    // one-time zero of slots 9 and 19 (never written in the loop)
    if (tid < 128) {
        Amsg[(9 + (tid >> 6) * 10) * 64 + (tid & 63)] = zero8;
    }
    __syncthreads();

    int it = 0;
    for (; tile < NTILES; tile += GRID, ++it) {
        const int p = it & 1;
        // ---------------- stage current tile (regs -> LDS) ----------------
        const int t = r2.x >> 20;
        const int ot = 1 - t;
        *(uint4*)&Amsg[(t * 10 + 2 * c) * 64 + row]     = q0;
        *(uint4*)&Amsg[(t * 10 + 2 * c + 1) * 64 + row] = q1;
        Amsg[(ot * 10 + 2 * c) * 64 + row]     = zero8;
        Amsg[(ot * 10 + 2 * c + 1) * 64 + row] = zero8;

        if (c == 0) {
            float d0 = cpd0 - cps0, d1 = cpd1 - cps1, d2 = cpd2 - cps2;
            float dist = sqrtf(d0 * d0 + d1 * d1 + d2 * d2);
            union { bf16x8 v; unsigned short u[8]; } pt;
            pt.u[0] = f2bf(cps0); pt.u[1] = f2bf(cps1); pt.u[2] = f2bf(cps2);
            pt.u[3] = f2bf(d0);   pt.u[4] = f2bf(d1);  pt.u[5] = f2bf(d2);
            pt.u[6] = f2bf(dist); pt.u[7] = f2bf(1.0f);
            Amsg[(t * 10 + 8) * 64 + row] = pt.v;
        } else if (c == 1) {
            Amsg[(ot * 10 + 8) * 64 + row] = zero8;
        } else if (c == 3) {
            dstv[p * 64 + row] = r2.y;
        }
        soft_barrier();                                    // B1 (lgkm only)

        // -------- prefetch next tile's rec (independent address) --------
        const int ntile = tile + GRID;
        const bool hasnext = (ntile < NTILES);
        int2 nr2 = r2;
        if (hasnext) nr2 = rec[ntile * TILE_E + row];

        // ---------------- mfma: 32x32 tile per wave, W from regs ----------------
        f32x4 acc00 = {0,0,0,0}, acc01 = {0,0,0,0}, acc10 = {0,0,0,0}, acc11 = {0,0,0,0};
        const int r0 = rg * 32 + la, r1 = r0 + 16;
        #pragma unroll
        for (int ks = 0; ks < 5; ++ks) {
            bf16x8 a0 = Amsg[(ks * 4 + lh) * 64 + r0];
            bf16x8 a1 = Amsg[(ks * 4 + lh) * 64 + r1];
            acc00 = MFMA16(a0, wb0[ks], acc00, 0, 0, 0);
            acc01 = MFMA16(a0, wb1[ks], acc01, 0, 0, 0);
            acc10 = MFMA16(a1, wb0[ks], acc10, 0, 0, 0);
            acc11 = MFMA16(a1, wb1[ks], acc11, 0, 0, 0);
        }

        // ---------------- keys -> Kt (swizzled, 2-way free) ----------------
        const int col0 = cg * 32 + la, col1 = col0 + 16;
        #pragma unroll
        for (int i = 0; i < 4; ++i) {
            int e0 = rg * 32 + lh * 4 + i, e1 = e0 + 16;
            Kt[e0 * 64 + (col0 ^ ((e0 << 2) & 31))] = fkey(acc00[i]);
            Kt[e0 * 64 + (col1 ^ ((e0 << 2) & 31))] = fkey(acc01[i]);
            Kt[e1 * 64 + (col0 ^ ((e1 << 2) & 31))] = fkey(acc10[i]);
            Kt[e1 * 64 + (col1 ^ ((e1 << 2) & 31))] = fkey(acc11[i]);
        }

        // -------- prefetch next tile's feat/pos (overlaps segscan) --------
        uint4 nq0 = q0, nq1 = q1;
        float nps0 = cps0, nps1 = cps1, nps2 = cps2;
        float npd0 = cpd0, npd1 = cpd1, npd2 = cpd2;
        if (hasnext) {
            int nsrc = nr2.x & 0xFFFFF;
            const uint4* ng = (const uint4*)(featbf + (size_t)nsrc * 64);
            nq0 = ng[2 * c]; nq1 = ng[2 * c + 1];
            if (c == 0) {
                nps0 = pos[nsrc * 3]; nps1 = pos[nsrc * 3 + 1]; nps2 = pos[nsrc * 3 + 2];
                int nd = nr2.y;
                npd0 = pos[nd * 3]; npd1 = pos[nd * 3 + 1]; npd2 = pos[nd * 3 + 2];
            }
        }

        soft_barrier();                                    // B2 (lgkm only)

        // ---- segmented max: thread (col, 16-row quarter), sorted dsts ----
        {
            const int colr = tid & 63;
            const int rbeg = (tid >> 6) * 16;
            unsigned cur = Kt[rbeg * 64 + (colr ^ ((rbeg << 2) & 31))];
            int curd = dstv[p * 64 + rbeg];
            #pragma unroll
            for (int r = rbeg + 1; r < rbeg + 16; ++r) {
                unsigned k = Kt[r * 64 + (colr ^ ((r << 2) & 31))];
                int d = dstv[p * 64 + r];
                if (d != curd) {
                    atomicMax(out + (size_t)curd * COUT + colr, cur);
                    curd = d; cur = k;
                } else {
                    cur = (k > cur) ? k : cur;
                }
            }
            atomicMax(out + (size_t)curd * COUT + colr, cur);
        }

        // ---------------- rotate prefetched regs ----------------
        r2 = nr2; q0 = nq0; q1 = nq1;
        cps0 = nps0; cps1 = nps1; cps2 = nps2;
        cpd0 = npd0; cpd1 = npd1; cpd2 = npd2;
        // hazards: staging(n+1) writes Amsg (all frag reads done pre-B2) and
        // dstv[p^1] (segscan reads dstv[p]); Kt(n+1) writes gated by B1(n+1).
    }
}

extern "C" void kernel_launch(void* const* d_in, const int* in_sizes, int n_in,
                              void* d_out, int out_size, void* d_ws, size_t ws_size,
                              hipStream_t stream) {
    const float* feat = (const float*)d_in[0];
    const float* pos  = (const float*)d_in[1];
    const float* W    = (const float*)d_in[2];
    const float* b    = (const float*)d_in[3];
    const int*   ei   = (const int*)d_in[4];
    const int*   ea   = (const int*)d_in[5];
    unsigned* out = (unsigned*)d_out;

    // ws: featbf 6.4MB | rec 6.4MB | cnt1 612KB | off0 612KB | totals | base
    unsigned short* featbf = (unsigned short*)d_ws;
    int2*     rec    = (int2*)((char*)d_ws + (size_t)NNODES * COUT * 2);
    unsigned* cnt1   = (unsigned*)(rec + NEDGES);
    unsigned* off0   = cnt1 + NB1 * NB1P;
    unsigned* totals = off0 + NB1 * NB1P;
    unsigned* base   = totals + NB1P;

    prep_kernel<<<2048, 256, 0, stream>>>(feat, featbf, out);
    p1a_kernel<<<NB1, 256, 0, stream>>>(ei, cnt1);
    p1b_kernel<<<NB1, 512, 0, stream>>>(cnt1, off0, totals);
    p1c_kernel<<<1, 512, 0, stream>>>(totals, base);
    p1d_kernel<<<NB1, 256, 0, stream>>>(ei, ea, off0, base, rec);
    p2_kernel<<<NB1, 512, 0, stream>>>(base, rec);
    edge_mfma_kernel<<<GRID, 256, 0, stream>>>(featbf, pos, W, b, rec, out);
    finalize_kernel<<<2048, 256, 0, stream>>>((float*)out, NNODES * COUT);
}